// Round 8
// baseline (416.799 us; speedup 1.0000x reference)
//
#include <hip/hip_runtime.h>

#define NNODES 50000
#define MPAD   50048    // padded to multiple of 128 for MFMA tiles
#define NEDGES 800000
#define KDIM   256      // in/hidden feature dim (GEMM K)
#define FH     256      // hidden feats
#define FOUT   128      // out feats

// ---- counting-sort geometry ----
#define SHIFT  8
#define NBUCK  196              // ceil(50000/256); max dst>>8 = 195
#define NB1    200              // level-1 blocks
#define EPB    4000             // edges per level-1 block (NB1*EPB == NEDGES)
#define CELLS  (NBUCK * NB1)    // 39200 per side
#define NSCAN  (2 * CELLS)      // 78400 (dst cells | src cells)
#define SCANB  ((NSCAN + 511) / 512)   // 154

typedef __bf16 bf16x8 __attribute__((ext_vector_type(8)));
typedef float floatx4 __attribute__((ext_vector_type(4)));

// ---------------- bf16 helpers (RNE) ----------------
__device__ __forceinline__ float bf2f(unsigned short u) {
    union { unsigned int i; float f; } v;
    v.i = ((unsigned int)u) << 16;
    return v.f;
}
__device__ __forceinline__ unsigned short f2bf(float f) {
    union { float f; unsigned int i; } v;
    v.f = f;
    unsigned int r = v.i + 0x7FFFu + ((v.i >> 16) & 1u);
    return (unsigned short)(r >> 16);
}

// ---------------- level-1: per-(block,bucket) histograms, no global atomics ----------------
__global__ __launch_bounds__(256) void l1_count(const int* __restrict__ src,
                                                const int* __restrict__ dst,
                                                int* __restrict__ cell) {
    __shared__ int histD[256], histS[256];
    const int b = blockIdx.x, tid = threadIdx.x;
    const int base = b * EPB;
    histD[tid] = 0; histS[tid] = 0;
    __syncthreads();
    for (int g = tid; g < EPB / 4; g += 256) {
        uint4 s4 = *(const uint4*)(src + base + g * 4);
        uint4 d4 = *(const uint4*)(dst + base + g * 4);
        atomicAdd(&histD[d4.x >> SHIFT], 1);
        atomicAdd(&histD[d4.y >> SHIFT], 1);
        atomicAdd(&histD[d4.z >> SHIFT], 1);
        atomicAdd(&histD[d4.w >> SHIFT], 1);
        atomicAdd(&histS[s4.x >> SHIFT], 1);
        atomicAdd(&histS[s4.y >> SHIFT], 1);
        atomicAdd(&histS[s4.z >> SHIFT], 1);
        atomicAdd(&histS[s4.w >> SHIFT], 1);
    }
    __syncthreads();
    if (tid < NBUCK) {
        cell[tid * NB1 + b] = histD[tid];
        cell[CELLS + tid * NB1 + b] = histS[tid];
    }
}

// ---------------- generic 3-kernel exclusive scan ----------------
__global__ __launch_bounds__(512) void scanA(int* __restrict__ data,
                                             int* __restrict__ sums, int n) {
    __shared__ int s[512];
    int tid = threadIdx.x;
    int i = blockIdx.x * 512 + tid;
    int v = (i < n) ? data[i] : 0;
    s[tid] = v;
    __syncthreads();
    for (int off = 1; off < 512; off <<= 1) {
        int t = (tid >= off) ? s[tid - off] : 0;
        __syncthreads();
        s[tid] += t;
        __syncthreads();
    }
    if (i < n) data[i] = s[tid] - v;
    if (tid == 511) sums[blockIdx.x] = s[511];
}

__global__ __launch_bounds__(512) void scanB(int* __restrict__ sums, int nb) {
    __shared__ int s[512];
    int tid = threadIdx.x;
    int v = (tid < nb) ? sums[tid] : 0;
    s[tid] = v;
    __syncthreads();
    for (int off = 1; off < 512; off <<= 1) {
        int t = (tid >= off) ? s[tid - off] : 0;
        __syncthreads();
        s[tid] += t;
        __syncthreads();
    }
    if (tid < nb) sums[tid] = s[tid] - v;
}

__global__ __launch_bounds__(512) void scanC(int* __restrict__ data,
                                             const int* __restrict__ sums, int n) {
    int i = blockIdx.x * 512 + threadIdx.x;
    if (i < n) data[i] += sums[blockIdx.x];
}

// ---------------- level-1 scatter: in-block counting sort, coalesced global writes --------
__global__ __launch_bounds__(256) void l1_scatter(const int* __restrict__ src,
                                                  const int* __restrict__ dst,
                                                  const int* __restrict__ cell,  // scanned
                                                  unsigned int* __restrict__ tmp1,
                                                  unsigned char* __restrict__ tmp2) {
    __shared__ int histD[256], histS[256];
    __shared__ int exD[256], exS[256];
    __shared__ unsigned int bufD[EPB];
    __shared__ unsigned short bufS[EPB];
    const int b = blockIdx.x, tid = threadIdx.x;
    const int base = b * EPB;

    histD[tid] = 0; histS[tid] = 0;
    __syncthreads();
    for (int g = tid; g < EPB / 4; g += 256) {
        uint4 s4 = *(const uint4*)(src + base + g * 4);
        uint4 d4 = *(const uint4*)(dst + base + g * 4);
        atomicAdd(&histD[d4.x >> SHIFT], 1);
        atomicAdd(&histD[d4.y >> SHIFT], 1);
        atomicAdd(&histD[d4.z >> SHIFT], 1);
        atomicAdd(&histD[d4.w >> SHIFT], 1);
        atomicAdd(&histS[s4.x >> SHIFT], 1);
        atomicAdd(&histS[s4.y >> SHIFT], 1);
        atomicAdd(&histS[s4.z >> SHIFT], 1);
        atomicAdd(&histS[s4.w >> SHIFT], 1);
    }
    __syncthreads();
    int vD = histD[tid], vS = histS[tid];
    exD[tid] = vD; exS[tid] = vS;
    __syncthreads();
    for (int off = 1; off < 256; off <<= 1) {
        int tD = (tid >= off) ? exD[tid - off] : 0;
        int tS = (tid >= off) ? exS[tid - off] : 0;
        __syncthreads();
        exD[tid] += tD; exS[tid] += tS;
        __syncthreads();
    }
    int eD = exD[tid] - vD, eS = exS[tid] - vS;
    __syncthreads();
    exD[tid] = eD; exS[tid] = eS;
    histD[tid] = eD; histS[tid] = eS;
    __syncthreads();
    for (int g = tid; g < EPB / 4; g += 256) {
        uint4 s4 = *(const uint4*)(src + base + g * 4);
        uint4 d4 = *(const uint4*)(dst + base + g * 4);
        unsigned int ss[4] = {s4.x, s4.y, s4.z, s4.w};
        unsigned int dd[4] = {d4.x, d4.y, d4.z, d4.w};
#pragma unroll
        for (int j = 0; j < 4; ++j) {
            int p = atomicAdd(&histD[dd[j] >> SHIFT], 1);
            bufD[p] = (ss[j] << 16) | dd[j];
            int q = atomicAdd(&histS[ss[j] >> SHIFT], 1);
            bufS[q] = (unsigned short)ss[j];
        }
    }
    __syncthreads();
    for (int e = tid; e < EPB; e += 256) {
        unsigned int p = bufD[e];
        int k = (p & 0xFFFFu) >> SHIFT;
        tmp1[cell[k * NB1 + b] + (e - exD[k])] = p;
    }
    for (int e = tid; e < EPB; e += 256) {
        unsigned int s = bufS[e];
        int k = s >> SHIFT;
        tmp2[(cell[CELLS + k * NB1 + b] - NEDGES) + (e - exS[k])] = (unsigned char)(s & 255u);
    }
}

// ---------------- level-2 dst: exact counts + row_ptr + norm_dst + csr scatter ------------
__global__ __launch_bounds__(256) void l2_dst(const unsigned int* __restrict__ tmp1,
                                              const int* __restrict__ cell,
                                              int* __restrict__ row_ptr,
                                              float* __restrict__ norm_dst,
                                              int* __restrict__ csr_src) {
    __shared__ int cnt[256], ofs[256], cur[256];
    const int k = blockIdx.x, tid = threadIdx.x;
    const int start = cell[k * NB1];
    const int end = (k + 1 < NBUCK) ? cell[(k + 1) * NB1] : NEDGES;
    cnt[tid] = 0;
    __syncthreads();
    for (int e = start + tid; e < end; e += 256)
        atomicAdd(&cnt[tmp1[e] & 255u], 1);
    __syncthreads();
    int v = cnt[tid];
    ofs[tid] = v;
    __syncthreads();
    for (int off = 1; off < 256; off <<= 1) {
        int t = (tid >= off) ? ofs[tid - off] : 0;
        __syncthreads();
        ofs[tid] += t;
        __syncthreads();
    }
    int excl = ofs[tid] - v;
    int node = k * 256 + tid;
    if (node < NNODES) {
        row_ptr[node] = start + excl;
        int d = v < 1 ? 1 : v;
        norm_dst[node] = 1.0f / sqrtf((float)d);
    }
    cur[tid] = start + excl;
    if (k == 0 && tid == 0) row_ptr[NNODES] = NEDGES;
    __syncthreads();
    for (int e = start + tid; e < end; e += 256) {
        unsigned int p = tmp1[e];
        int pos = atomicAdd(&cur[p & 255u], 1);
        csr_src[pos] = (int)(p >> 16);
    }
}

// ---------------- level-2 src: counts -> norm_src ----------------
__global__ __launch_bounds__(256) void l2_src(const unsigned char* __restrict__ tmp2,
                                              const int* __restrict__ cell,
                                              float* __restrict__ norm_src) {
    __shared__ int cnt[256];
    const int k = blockIdx.x, tid = threadIdx.x;
    const int start = cell[CELLS + k * NB1] - NEDGES;
    const int end = (k + 1 < NBUCK) ? cell[CELLS + (k + 1) * NB1] - NEDGES : NEDGES;
    cnt[tid] = 0;
    __syncthreads();
    for (int e = start + tid; e < end; e += 256)
        atomicAdd(&cnt[tmp2[e]], 1);
    __syncthreads();
    int node = k * 256 + tid;
    if (node < NNODES) {
        int d = cnt[tid] < 1 ? 1 : cnt[tid];
        norm_src[node] = 1.0f / sqrtf((float)d);
    }
}

// ---------------- W1,W2 [K][N] -> Wt [N][K] bf16 (one kernel, LDS 32x32 transpose) --------
__global__ __launch_bounds__(256) void cast_wt_both(const float* __restrict__ W1,
                                                    unsigned short* __restrict__ Wt1,
                                                    const float* __restrict__ W2,
                                                    unsigned short* __restrict__ Wt2) {
    __shared__ float tile[32][33];
    int b = blockIdx.x;
    const float* W; unsigned short* Wt; int N;
    if (b < 64) { W = W1; Wt = Wt1; N = FH; }
    else        { b -= 64; W = W2; Wt = Wt2; N = FOUT; }
    int kt = (b & 7) * 32;
    int nt = (b >> 3) * 32;
    int tx = threadIdx.x & 31;
    int ty = threadIdx.x >> 5;
    for (int r = ty; r < 32; r += 8)
        tile[r][tx] = W[(size_t)(kt + r) * N + nt + tx];
    __syncthreads();
    for (int r = ty; r < 32; r += 8)
        Wt[(size_t)(nt + r) * KDIM + kt + tx] = f2bf(tile[tx][r]);
}

// ---------------- A-staging loaders (8 bf16 = 16B, packed in uint4) ----------------
__device__ __forceinline__ uint4 stage_a8(const float* A, int row, int k, float scale, bool valid) {
    if (!valid) return make_uint4(0u, 0u, 0u, 0u);
    const float* p = A + (size_t)row * KDIM + k;
    float4 v0 = *(const float4*)p;
    float4 v1 = *(const float4*)(p + 4);
    union { uint4 u; unsigned short s[8]; } r;
    r.s[0] = f2bf(v0.x * scale); r.s[1] = f2bf(v0.y * scale);
    r.s[2] = f2bf(v0.z * scale); r.s[3] = f2bf(v0.w * scale);
    r.s[4] = f2bf(v1.x * scale); r.s[5] = f2bf(v1.y * scale);
    r.s[6] = f2bf(v1.z * scale); r.s[7] = f2bf(v1.w * scale);
    return r.u;
}
__device__ __forceinline__ uint4 stage_a8(const unsigned short* A, int row, int k, float, bool) {
    return *(const uint4*)(A + (size_t)row * KDIM + k);
}

// ---------------- bf16 MFMA GEMM: C[M,N] = (A[M,256] * norm?) @ Bt[N,256]^T ----------------
template <typename TA, bool SCALE>
__global__ __launch_bounds__(256) void gemm_mfma(const TA* __restrict__ A,
                                                 const unsigned short* __restrict__ Bt,
                                                 const float* __restrict__ norm,
                                                 unsigned short* __restrict__ C,
                                                 int N) {
    __shared__ __align__(16) unsigned short As[128][32];
    __shared__ __align__(16) unsigned short Bs[128][32];

    const int tid = threadIdx.x;
    const int lane = tid & 63;
    const int wave = tid >> 6;
    const int wm = wave & 1, wn = wave >> 1;
    const int m0 = blockIdx.x * 128;
    const int n0 = blockIdx.y * 128;

    const int srow = tid >> 2;
    const int sk = (tid & 3) << 3;

    const int r0 = m0 + srow;
    const int r1 = r0 + 64;
    bool va0 = true, va1 = true;
    float sc0 = 0.f, sc1 = 0.f;
    if (SCALE) {
        va0 = (r0 < NNODES); va1 = (r1 < NNODES);
        sc0 = va0 ? norm[r0] : 0.f;
        sc1 = va1 ? norm[r1] : 0.f;
    }

    const unsigned short* Bg = Bt + (size_t)(n0 + srow) * KDIM + sk;

    floatx4 acc[4][4] = {};

    const int ar = wm * 64 + (lane & 15);
    const int br = wn * 64 + (lane & 15);
    const int fk = (lane >> 4) << 3;

    for (int kk = 0; kk < KDIM; kk += 32) {
        uint4 a0 = stage_a8(A, va0 ? r0 : 0, kk + sk, sc0, va0);
        uint4 a1 = stage_a8(A, va1 ? r1 : 0, kk + sk, sc1, va1);
        uint4 b0 = *(const uint4*)(Bg + kk);
        uint4 b1 = *(const uint4*)(Bg + (size_t)64 * KDIM + kk);
        __syncthreads();
        *(uint4*)&As[srow][sk] = a0;
        *(uint4*)&As[srow + 64][sk] = a1;
        *(uint4*)&Bs[srow][sk] = b0;
        *(uint4*)&Bs[srow + 64][sk] = b1;
        __syncthreads();

        bf16x8 af[4], bfr[4];
#pragma unroll
        for (int i = 0; i < 4; ++i) {
            af[i]  = *(const bf16x8*)&As[ar + i * 16][fk];
            bfr[i] = *(const bf16x8*)&Bs[br + i * 16][fk];
        }
#pragma unroll
        for (int i = 0; i < 4; ++i)
#pragma unroll
            for (int j = 0; j < 4; ++j)
                acc[i][j] = __builtin_amdgcn_mfma_f32_16x16x32_bf16(af[i], bfr[j], acc[i][j], 0, 0, 0);
    }

    const int rb = (lane >> 4) << 2;
    const int cc = lane & 15;
#pragma unroll
    for (int i = 0; i < 4; ++i) {
        int mb = m0 + wm * 64 + i * 16 + rb;
#pragma unroll
        for (int j = 0; j < 4; ++j) {
            int col = n0 + wn * 64 + j * 16 + cc;
#pragma unroll
            for (int r = 0; r < 4; ++r) {
                int m = mb + r;
                if (m < NNODES)
                    C[(size_t)m * N + col] = f2bf(acc[i][j][r]);
            }
        }
    }
}

// ---------------- agg layer 1, feature-sliced for XCD L2 affinity ----------------
// slice = blockIdx % 8 (32 bf16 feats = 64B; per-XCD working set 3.2MB < 4MB L2 if the
// round-robin blockIdx%8 -> XCD dispatch heuristic holds). One wave per (node,slice):
// 4 quarter-waves process 4 edges concurrently (lane = 16*q + featpair, ushort2 loads),
// butterfly shfl reduction, quarter-wave 0 stores.
__global__ __launch_bounds__(256) void agg1_kernel(const unsigned short* __restrict__ H,
                                                   const int* __restrict__ row_ptr,
                                                   const int* __restrict__ csr_src,
                                                   const float* __restrict__ norm_dst,
                                                   const float* __restrict__ norm_src,
                                                   const float* __restrict__ bias,
                                                   unsigned short* __restrict__ out) {
    const int F = 256;
    const int slice = blockIdx.x & 7;
    const int node = (blockIdx.x >> 3) * 4 + (threadIdx.x >> 6);
    const int lane = threadIdx.x & 63;
    const int q = lane >> 4;           // edge slot 0..3
    const int j = lane & 15;           // feat pair 0..15
    const int f0 = slice * 32 + j * 2;

    if (node >= NNODES) {
        if (node < MPAD && q == 0) {
            ushort2 z = {0, 0};
            *(ushort2*)(out + (size_t)node * F + f0) = z;
        }
        return;
    }
    int e0 = row_ptr[node];
    int e1 = row_ptr[node + 1];

    float acc0 = 0.f, acc1 = 0.f;
    const unsigned short* Hl = H + f0;

    int e = e0 + q;
    // 2x unrolled over stride-4 (8 loads in flight per wave)
    for (; e + 4 < e1; e += 8) {
        int s0 = csr_src[e];
        int s1 = csr_src[e + 4];
        ushort2 v0 = *(const ushort2*)(Hl + (size_t)s0 * F);
        ushort2 v1 = *(const ushort2*)(Hl + (size_t)s1 * F);
        acc0 += bf2f(v0.x) + bf2f(v1.x);
        acc1 += bf2f(v0.y) + bf2f(v1.y);
    }
    if (e < e1) {
        int s0 = csr_src[e];
        ushort2 v0 = *(const ushort2*)(Hl + (size_t)s0 * F);
        acc0 += bf2f(v0.x);
        acc1 += bf2f(v0.y);
    }
    // reduce across the 4 edge slots (lanes differing in bits 4,5)
    acc0 += __shfl_xor(acc0, 16); acc1 += __shfl_xor(acc1, 16);
    acc0 += __shfl_xor(acc0, 32); acc1 += __shfl_xor(acc1, 32);

    if (q == 0) {
        float nd = norm_dst[node];
        float ns = norm_src[node];
        float o0 = fmaxf(fmaf(acc0, nd, bias[f0 + 0]), 0.0f) * ns;
        float o1 = fmaxf(fmaf(acc1, nd, bias[f0 + 1]), 0.0f) * ns;
        ushort2 o;
        o.x = f2bf(o0); o.y = f2bf(o1);
        *(ushort2*)(out + (size_t)node * F + f0) = o;
    }
}

// ---------------- agg layer 2, feature-sliced (4 slices x 2 dst-halves = 8 XCD groups) ----
__global__ __launch_bounds__(256) void agg2_kernel(const unsigned short* __restrict__ H,
                                                   const int* __restrict__ row_ptr,
                                                   const int* __restrict__ csr_src,
                                                   const float* __restrict__ norm_dst,
                                                   const float* __restrict__ bias,
                                                   float* __restrict__ out) {
    const int F = 128;
    const int xg = blockIdx.x & 7;
    const int slice = xg & 3;
    const int half = xg >> 2;
    const int node = half * (NNODES / 2) + (blockIdx.x >> 3) * 4 + (threadIdx.x >> 6);
    const int lane = threadIdx.x & 63;
    const int q = lane >> 4;
    const int j = lane & 15;
    const int f0 = slice * 32 + j * 2;

    int e0 = row_ptr[node];
    int e1 = row_ptr[node + 1];

    float acc0 = 0.f, acc1 = 0.f;
    const unsigned short* Hl = H + f0;

    int e = e0 + q;
    for (; e + 4 < e1; e += 8) {
        int s0 = csr_src[e];
        int s1 = csr_src[e + 4];
        ushort2 v0 = *(const ushort2*)(Hl + (size_t)s0 * F);
        ushort2 v1 = *(const ushort2*)(Hl + (size_t)s1 * F);
        acc0 += bf2f(v0.x) + bf2f(v1.x);
        acc1 += bf2f(v0.y) + bf2f(v1.y);
    }
    if (e < e1) {
        int s0 = csr_src[e];
        ushort2 v0 = *(const ushort2*)(Hl + (size_t)s0 * F);
        acc0 += bf2f(v0.x);
        acc1 += bf2f(v0.y);
    }
    acc0 += __shfl_xor(acc0, 16); acc1 += __shfl_xor(acc1, 16);
    acc0 += __shfl_xor(acc0, 32); acc1 += __shfl_xor(acc1, 32);

    if (q == 0) {
        float nd = norm_dst[node];
        float2 o;
        o.x = fmaf(acc0, nd, bias[f0 + 0]);
        o.y = fmaf(acc1, nd, bias[f0 + 1]);
        *(float2*)(out + (size_t)node * F + f0) = o;
    }
}

// ---------------- launch ----------------
extern "C" void kernel_launch(void* const* d_in, const int* in_sizes, int n_in,
                              void* d_out, int out_size, void* d_ws, size_t ws_size,
                              hipStream_t stream) {
    const float* x   = (const float*)d_in[0];
    const int*   src = (const int*)d_in[1];
    const int*   dst = (const int*)d_in[2];
    const float* W1  = (const float*)d_in[3];
    const float* b1  = (const float*)d_in[4];
    const float* W2  = (const float*)d_in[5];
    const float* b2  = (const float*)d_in[6];
    float* out = (float*)d_out;

    char* ws = (char*)d_ws;
    size_t off = 0;
    auto alloc = [&](size_t bytes) {
        char* p = ws + off;
        off += (bytes + 255) & ~(size_t)255;
        return p;
    };
    float* norm_src  = (float*)alloc(NNODES * 4);
    float* norm_dst  = (float*)alloc(NNODES * 4);
    int*   cell      = (int*)alloc((size_t)NSCAN * 4);
    int*   ssum      = (int*)alloc(512 * 4);
    unsigned int*  tmp1 = (unsigned int*)alloc((size_t)NEDGES * 4);
    unsigned char* tmp2 = (unsigned char*)alloc((size_t)NEDGES);
    int*   row_ptr   = (int*)alloc((NNODES + 16) * 4);
    int*   csr_src   = (int*)alloc(NEDGES * 4);
    unsigned short* h   = (unsigned short*)alloc((size_t)NNODES * FH * 2);
    unsigned short* h1  = (unsigned short*)alloc((size_t)MPAD * FH * 2);
    unsigned short* Wt1 = (unsigned short*)alloc((size_t)FH * KDIM * 2);
    unsigned short* Wt2 = (unsigned short*)alloc((size_t)FOUT * KDIM * 2);
    unsigned short* h2  = h;

    cast_wt_both<<<96, 256, 0, stream>>>(W1, Wt1, W2, Wt2);

    l1_count<<<NB1, 256, 0, stream>>>(src, dst, cell);
    scanA<<<SCANB, 512, 0, stream>>>(cell, ssum, NSCAN);
    scanB<<<1, 512, 0, stream>>>(ssum, SCANB);
    scanC<<<SCANB, 512, 0, stream>>>(cell, ssum, NSCAN);
    l1_scatter<<<NB1, 256, 0, stream>>>(src, dst, cell, tmp1, tmp2);
    l2_dst<<<NBUCK, 256, 0, stream>>>(tmp1, cell, row_ptr, norm_dst, csr_src);
    l2_src<<<NBUCK, 256, 0, stream>>>(tmp2, cell, norm_src);

    // layer 1: h = bf16((x*norm_src) @ W1)
    gemm_mfma<float, true><<<dim3(MPAD / 128, FH / 128), 256, 0, stream>>>(x, Wt1, norm_src, h, FH);
    // h1 = bf16(relu(agg(h)*norm_dst + b1) * norm_src); 8 feature slices, XCD-affine
    agg1_kernel<<<8 * (MPAD / 4), 256, 0, stream>>>(h, row_ptr, csr_src, norm_dst, norm_src, b1, h1);

    // layer 2
    gemm_mfma<unsigned short, false><<<dim3(MPAD / 128, FOUT / 128), 256, 0, stream>>>(h1, Wt2, nullptr, h2, FOUT);
    agg2_kernel<<<8 * (NNODES / 2 / 4), 256, 0, stream>>>(h2, row_ptr, csr_src, norm_dst, b2, out);
}

// Round 9
// 266.643 us; speedup vs baseline: 1.5631x; 1.5631x over previous
//
#include <hip/hip_runtime.h>

#define NNODES 50000
#define MPAD   50048    // padded to multiple of 128 for MFMA tiles
#define NEDGES 800000
#define KDIM   256      // in/hidden feature dim (GEMM K)
#define FH     256      // hidden feats
#define FOUT   128      // out feats

// ---- counting-sort geometry ----
#define SHIFT  8
#define NBUCK  196              // ceil(50000/256); max dst>>8 = 195
#define NB1    200              // level-1 blocks
#define EPB    4000             // edges per level-1 block (NB1*EPB == NEDGES)
#define CELLS  (NBUCK * NB1)    // 39200 per side
#define NSCAN  (2 * CELLS)      // 78400 (dst cells | src cells)
#define SCANB  ((NSCAN + 511) / 512)   // 154

typedef __bf16 bf16x8 __attribute__((ext_vector_type(8)));
typedef float floatx4 __attribute__((ext_vector_type(4)));

// ---------------- bf16 helpers (RNE) ----------------
__device__ __forceinline__ float bf2f(unsigned short u) {
    union { unsigned int i; float f; } v;
    v.i = ((unsigned int)u) << 16;
    return v.f;
}
__device__ __forceinline__ unsigned short f2bf(float f) {
    union { float f; unsigned int i; } v;
    v.f = f;
    unsigned int r = v.i + 0x7FFFu + ((v.i >> 16) & 1u);
    return (unsigned short)(r >> 16);
}

// ---------------- level-1: per-(block,bucket) histograms, no global atomics ----------------
__global__ __launch_bounds__(256) void l1_count(const int* __restrict__ src,
                                                const int* __restrict__ dst,
                                                int* __restrict__ cell) {
    __shared__ int histD[256], histS[256];
    const int b = blockIdx.x, tid = threadIdx.x;
    const int base = b * EPB;
    histD[tid] = 0; histS[tid] = 0;
    __syncthreads();
    for (int g = tid; g < EPB / 4; g += 256) {
        uint4 s4 = *(const uint4*)(src + base + g * 4);
        uint4 d4 = *(const uint4*)(dst + base + g * 4);
        atomicAdd(&histD[d4.x >> SHIFT], 1);
        atomicAdd(&histD[d4.y >> SHIFT], 1);
        atomicAdd(&histD[d4.z >> SHIFT], 1);
        atomicAdd(&histD[d4.w >> SHIFT], 1);
        atomicAdd(&histS[s4.x >> SHIFT], 1);
        atomicAdd(&histS[s4.y >> SHIFT], 1);
        atomicAdd(&histS[s4.z >> SHIFT], 1);
        atomicAdd(&histS[s4.w >> SHIFT], 1);
    }
    __syncthreads();
    if (tid < NBUCK) {
        cell[tid * NB1 + b] = histD[tid];
        cell[CELLS + tid * NB1 + b] = histS[tid];
    }
}

// ---------------- generic 3-kernel exclusive scan ----------------
__global__ __launch_bounds__(512) void scanA(int* __restrict__ data,
                                             int* __restrict__ sums, int n) {
    __shared__ int s[512];
    int tid = threadIdx.x;
    int i = blockIdx.x * 512 + tid;
    int v = (i < n) ? data[i] : 0;
    s[tid] = v;
    __syncthreads();
    for (int off = 1; off < 512; off <<= 1) {
        int t = (tid >= off) ? s[tid - off] : 0;
        __syncthreads();
        s[tid] += t;
        __syncthreads();
    }
    if (i < n) data[i] = s[tid] - v;
    if (tid == 511) sums[blockIdx.x] = s[511];
}

__global__ __launch_bounds__(512) void scanB(int* __restrict__ sums, int nb) {
    __shared__ int s[512];
    int tid = threadIdx.x;
    int v = (tid < nb) ? sums[tid] : 0;
    s[tid] = v;
    __syncthreads();
    for (int off = 1; off < 512; off <<= 1) {
        int t = (tid >= off) ? s[tid - off] : 0;
        __syncthreads();
        s[tid] += t;
        __syncthreads();
    }
    if (tid < nb) sums[tid] = s[tid] - v;
}

__global__ __launch_bounds__(512) void scanC(int* __restrict__ data,
                                             const int* __restrict__ sums, int n) {
    int i = blockIdx.x * 512 + threadIdx.x;
    if (i < n) data[i] += sums[blockIdx.x];
}

// ---------------- level-1 scatter: in-block counting sort, coalesced global writes --------
__global__ __launch_bounds__(256) void l1_scatter(const int* __restrict__ src,
                                                  const int* __restrict__ dst,
                                                  const int* __restrict__ cell,  // scanned
                                                  unsigned int* __restrict__ tmp1,
                                                  unsigned char* __restrict__ tmp2) {
    __shared__ int histD[256], histS[256];
    __shared__ int exD[256], exS[256];
    __shared__ unsigned int bufD[EPB];
    __shared__ unsigned short bufS[EPB];
    const int b = blockIdx.x, tid = threadIdx.x;
    const int base = b * EPB;

    histD[tid] = 0; histS[tid] = 0;
    __syncthreads();
    for (int g = tid; g < EPB / 4; g += 256) {
        uint4 s4 = *(const uint4*)(src + base + g * 4);
        uint4 d4 = *(const uint4*)(dst + base + g * 4);
        atomicAdd(&histD[d4.x >> SHIFT], 1);
        atomicAdd(&histD[d4.y >> SHIFT], 1);
        atomicAdd(&histD[d4.z >> SHIFT], 1);
        atomicAdd(&histD[d4.w >> SHIFT], 1);
        atomicAdd(&histS[s4.x >> SHIFT], 1);
        atomicAdd(&histS[s4.y >> SHIFT], 1);
        atomicAdd(&histS[s4.z >> SHIFT], 1);
        atomicAdd(&histS[s4.w >> SHIFT], 1);
    }
    __syncthreads();
    int vD = histD[tid], vS = histS[tid];
    exD[tid] = vD; exS[tid] = vS;
    __syncthreads();
    for (int off = 1; off < 256; off <<= 1) {
        int tD = (tid >= off) ? exD[tid - off] : 0;
        int tS = (tid >= off) ? exS[tid - off] : 0;
        __syncthreads();
        exD[tid] += tD; exS[tid] += tS;
        __syncthreads();
    }
    int eD = exD[tid] - vD, eS = exS[tid] - vS;
    __syncthreads();
    exD[tid] = eD; exS[tid] = eS;
    histD[tid] = eD; histS[tid] = eS;
    __syncthreads();
    for (int g = tid; g < EPB / 4; g += 256) {
        uint4 s4 = *(const uint4*)(src + base + g * 4);
        uint4 d4 = *(const uint4*)(dst + base + g * 4);
        unsigned int ss[4] = {s4.x, s4.y, s4.z, s4.w};
        unsigned int dd[4] = {d4.x, d4.y, d4.z, d4.w};
#pragma unroll
        for (int j = 0; j < 4; ++j) {
            int p = atomicAdd(&histD[dd[j] >> SHIFT], 1);
            bufD[p] = (ss[j] << 16) | dd[j];
            int q = atomicAdd(&histS[ss[j] >> SHIFT], 1);
            bufS[q] = (unsigned short)ss[j];
        }
    }
    __syncthreads();
    for (int e = tid; e < EPB; e += 256) {
        unsigned int p = bufD[e];
        int k = (p & 0xFFFFu) >> SHIFT;
        tmp1[cell[k * NB1 + b] + (e - exD[k])] = p;
    }
    for (int e = tid; e < EPB; e += 256) {
        unsigned int s = bufS[e];
        int k = s >> SHIFT;
        tmp2[(cell[CELLS + k * NB1 + b] - NEDGES) + (e - exS[k])] = (unsigned char)(s & 255u);
    }
}

// ---------------- level-2 dst: exact counts + row_ptr + norm_dst + csr scatter ------------
__global__ __launch_bounds__(256) void l2_dst(const unsigned int* __restrict__ tmp1,
                                              const int* __restrict__ cell,
                                              int* __restrict__ row_ptr,
                                              float* __restrict__ norm_dst,
                                              int* __restrict__ csr_src) {
    __shared__ int cnt[256], ofs[256], cur[256];
    const int k = blockIdx.x, tid = threadIdx.x;
    const int start = cell[k * NB1];
    const int end = (k + 1 < NBUCK) ? cell[(k + 1) * NB1] : NEDGES;
    cnt[tid] = 0;
    __syncthreads();
    for (int e = start + tid; e < end; e += 256)
        atomicAdd(&cnt[tmp1[e] & 255u], 1);
    __syncthreads();
    int v = cnt[tid];
    ofs[tid] = v;
    __syncthreads();
    for (int off = 1; off < 256; off <<= 1) {
        int t = (tid >= off) ? ofs[tid - off] : 0;
        __syncthreads();
        ofs[tid] += t;
        __syncthreads();
    }
    int excl = ofs[tid] - v;
    int node = k * 256 + tid;
    if (node < NNODES) {
        row_ptr[node] = start + excl;
        int d = v < 1 ? 1 : v;
        norm_dst[node] = 1.0f / sqrtf((float)d);
    }
    cur[tid] = start + excl;
    if (k == 0 && tid == 0) row_ptr[NNODES] = NEDGES;
    __syncthreads();
    for (int e = start + tid; e < end; e += 256) {
        unsigned int p = tmp1[e];
        int pos = atomicAdd(&cur[p & 255u], 1);
        csr_src[pos] = (int)(p >> 16);
    }
}

// ---------------- level-2 src: counts -> norm_src ----------------
__global__ __launch_bounds__(256) void l2_src(const unsigned char* __restrict__ tmp2,
                                              const int* __restrict__ cell,
                                              float* __restrict__ norm_src) {
    __shared__ int cnt[256];
    const int k = blockIdx.x, tid = threadIdx.x;
    const int start = cell[CELLS + k * NB1] - NEDGES;
    const int end = (k + 1 < NBUCK) ? cell[CELLS + (k + 1) * NB1] - NEDGES : NEDGES;
    cnt[tid] = 0;
    __syncthreads();
    for (int e = start + tid; e < end; e += 256)
        atomicAdd(&cnt[tmp2[e]], 1);
    __syncthreads();
    int node = k * 256 + tid;
    if (node < NNODES) {
        int d = cnt[tid] < 1 ? 1 : cnt[tid];
        norm_src[node] = 1.0f / sqrtf((float)d);
    }
}

// ---------------- W1,W2 [K][N] -> Wt [N][K] bf16 (one kernel, LDS 32x32 transpose) --------
__global__ __launch_bounds__(256) void cast_wt_both(const float* __restrict__ W1,
                                                    unsigned short* __restrict__ Wt1,
                                                    const float* __restrict__ W2,
                                                    unsigned short* __restrict__ Wt2) {
    __shared__ float tile[32][33];
    int b = blockIdx.x;
    const float* W; unsigned short* Wt; int N;
    if (b < 64) { W = W1; Wt = Wt1; N = FH; }
    else        { b -= 64; W = W2; Wt = Wt2; N = FOUT; }
    int kt = (b & 7) * 32;
    int nt = (b >> 3) * 32;
    int tx = threadIdx.x & 31;
    int ty = threadIdx.x >> 5;
    for (int r = ty; r < 32; r += 8)
        tile[r][tx] = W[(size_t)(kt + r) * N + nt + tx];
    __syncthreads();
    for (int r = ty; r < 32; r += 8)
        Wt[(size_t)(nt + r) * KDIM + kt + tx] = f2bf(tile[tx][r]);
}

// ---------------- A-staging loaders (8 bf16 = 16B, packed in uint4) ----------------
__device__ __forceinline__ uint4 stage_a8(const float* A, int row, int k, float scale, bool valid) {
    if (!valid) return make_uint4(0u, 0u, 0u, 0u);
    const float* p = A + (size_t)row * KDIM + k;
    float4 v0 = *(const float4*)p;
    float4 v1 = *(const float4*)(p + 4);
    union { uint4 u; unsigned short s[8]; } r;
    r.s[0] = f2bf(v0.x * scale); r.s[1] = f2bf(v0.y * scale);
    r.s[2] = f2bf(v0.z * scale); r.s[3] = f2bf(v0.w * scale);
    r.s[4] = f2bf(v1.x * scale); r.s[5] = f2bf(v1.y * scale);
    r.s[6] = f2bf(v1.z * scale); r.s[7] = f2bf(v1.w * scale);
    return r.u;
}
__device__ __forceinline__ uint4 stage_a8(const unsigned short* A, int row, int k, float, bool) {
    return *(const uint4*)(A + (size_t)row * KDIM + k);
}

// ---------------- bf16 MFMA GEMM: C[M,N] = (A[M,256] * norm?) @ Bt[N,256]^T ----------------
template <typename TA, bool SCALE>
__global__ __launch_bounds__(256) void gemm_mfma(const TA* __restrict__ A,
                                                 const unsigned short* __restrict__ Bt,
                                                 const float* __restrict__ norm,
                                                 unsigned short* __restrict__ C,
                                                 int N) {
    __shared__ __align__(16) unsigned short As[128][32];
    __shared__ __align__(16) unsigned short Bs[128][32];

    const int tid = threadIdx.x;
    const int lane = tid & 63;
    const int wave = tid >> 6;
    const int wm = wave & 1, wn = wave >> 1;
    const int m0 = blockIdx.x * 128;
    const int n0 = blockIdx.y * 128;

    const int srow = tid >> 2;
    const int sk = (tid & 3) << 3;

    const int r0 = m0 + srow;
    const int r1 = r0 + 64;
    bool va0 = true, va1 = true;
    float sc0 = 0.f, sc1 = 0.f;
    if (SCALE) {
        va0 = (r0 < NNODES); va1 = (r1 < NNODES);
        sc0 = va0 ? norm[r0] : 0.f;
        sc1 = va1 ? norm[r1] : 0.f;
    }

    const unsigned short* Bg = Bt + (size_t)(n0 + srow) * KDIM + sk;

    floatx4 acc[4][4] = {};

    const int ar = wm * 64 + (lane & 15);
    const int br = wn * 64 + (lane & 15);
    const int fk = (lane >> 4) << 3;

    for (int kk = 0; kk < KDIM; kk += 32) {
        uint4 a0 = stage_a8(A, va0 ? r0 : 0, kk + sk, sc0, va0);
        uint4 a1 = stage_a8(A, va1 ? r1 : 0, kk + sk, sc1, va1);
        uint4 b0 = *(const uint4*)(Bg + kk);
        uint4 b1 = *(const uint4*)(Bg + (size_t)64 * KDIM + kk);
        __syncthreads();
        *(uint4*)&As[srow][sk] = a0;
        *(uint4*)&As[srow + 64][sk] = a1;
        *(uint4*)&Bs[srow][sk] = b0;
        *(uint4*)&Bs[srow + 64][sk] = b1;
        __syncthreads();

        bf16x8 af[4], bfr[4];
#pragma unroll
        for (int i = 0; i < 4; ++i) {
            af[i]  = *(const bf16x8*)&As[ar + i * 16][fk];
            bfr[i] = *(const bf16x8*)&Bs[br + i * 16][fk];
        }
#pragma unroll
        for (int i = 0; i < 4; ++i)
#pragma unroll
            for (int j = 0; j < 4; ++j)
                acc[i][j] = __builtin_amdgcn_mfma_f32_16x16x32_bf16(af[i], bfr[j], acc[i][j], 0, 0, 0);
    }

    const int rb = (lane >> 4) << 2;
    const int cc = lane & 15;
#pragma unroll
    for (int i = 0; i < 4; ++i) {
        int mb = m0 + wm * 64 + i * 16 + rb;
#pragma unroll
        for (int j = 0; j < 4; ++j) {
            int col = n0 + wn * 64 + j * 16 + cc;
#pragma unroll
            for (int r = 0; r < 4; ++r) {
                int m = mb + r;
                if (m < NNODES)
                    C[(size_t)m * N + col] = f2bf(acc[i][j][r]);
            }
        }
    }
}

// ---------------- agg layer 1: bf16 in (F=256), bf16 out. Full row per wave (R7 layout),
// 8-deep + 4-deep + scalar unroll for MLP. h1 = relu(agg*norm_dst+b1)*norm_src; pad rows zero.
__global__ __launch_bounds__(256) void agg1_kernel(const unsigned short* __restrict__ H,
                                                   const int* __restrict__ row_ptr,
                                                   const int* __restrict__ csr_src,
                                                   const float* __restrict__ norm_dst,
                                                   const float* __restrict__ norm_src,
                                                   const float* __restrict__ bias,
                                                   unsigned short* __restrict__ out) {
    const int F = 256;
    int node = blockIdx.x * 4 + (threadIdx.x >> 6);
    int lane = threadIdx.x & 63;
    int f0 = lane * 4;
    if (node >= NNODES) {
        if (node < MPAD) {
            ushort4 z = {0, 0, 0, 0};
            *(ushort4*)(out + (size_t)node * F + f0) = z;
        }
        return;
    }
    int e0 = row_ptr[node];
    int e1 = row_ptr[node + 1];

    float acc0 = 0.f, acc1 = 0.f, acc2 = 0.f, acc3 = 0.f;
    const unsigned short* Hl = H + f0;

    int e = e0;
    for (; e + 7 < e1; e += 8) {
        ushort4 v[8];
#pragma unroll
        for (int u = 0; u < 8; ++u)
            v[u] = *(const ushort4*)(Hl + (size_t)csr_src[e + u] * F);
#pragma unroll
        for (int u = 0; u < 8; ++u) {
            acc0 += bf2f(v[u].x); acc1 += bf2f(v[u].y);
            acc2 += bf2f(v[u].z); acc3 += bf2f(v[u].w);
        }
    }
    for (; e + 3 < e1; e += 4) {
        ushort4 v[4];
#pragma unroll
        for (int u = 0; u < 4; ++u)
            v[u] = *(const ushort4*)(Hl + (size_t)csr_src[e + u] * F);
#pragma unroll
        for (int u = 0; u < 4; ++u) {
            acc0 += bf2f(v[u].x); acc1 += bf2f(v[u].y);
            acc2 += bf2f(v[u].z); acc3 += bf2f(v[u].w);
        }
    }
    for (; e < e1; ++e) {
        ushort4 v = *(const ushort4*)(Hl + (size_t)csr_src[e] * F);
        acc0 += bf2f(v.x); acc1 += bf2f(v.y); acc2 += bf2f(v.z); acc3 += bf2f(v.w);
    }

    float nd = norm_dst[node];
    float ns = norm_src[node];
    float o0 = fmaxf(fmaf(acc0, nd, bias[f0 + 0]), 0.0f) * ns;
    float o1 = fmaxf(fmaf(acc1, nd, bias[f0 + 1]), 0.0f) * ns;
    float o2 = fmaxf(fmaf(acc2, nd, bias[f0 + 2]), 0.0f) * ns;
    float o3 = fmaxf(fmaf(acc3, nd, bias[f0 + 3]), 0.0f) * ns;
    ushort4 o;
    o.x = f2bf(o0); o.y = f2bf(o1); o.z = f2bf(o2); o.w = f2bf(o3);
    *(ushort4*)(out + (size_t)node * F + f0) = o;
}

// ---------------- agg layer 2: bf16 in (F=128), fp32 out, no relu. Half-wave per node. ----
__global__ __launch_bounds__(256) void agg2_kernel(const unsigned short* __restrict__ H,
                                                   const int* __restrict__ row_ptr,
                                                   const int* __restrict__ csr_src,
                                                   const float* __restrict__ norm_dst,
                                                   const float* __restrict__ bias,
                                                   float* __restrict__ out) {
    const int F = 128;
    int node = blockIdx.x * 8 + (threadIdx.x >> 5);
    if (node >= NNODES) return;
    int lane = threadIdx.x & 31;
    int f0 = lane * 4;
    int e0 = row_ptr[node];
    int e1 = row_ptr[node + 1];

    float acc0 = 0.f, acc1 = 0.f, acc2 = 0.f, acc3 = 0.f;
    const unsigned short* Hl = H + f0;

    int e = e0;
    for (; e + 7 < e1; e += 8) {
        ushort4 v[8];
#pragma unroll
        for (int u = 0; u < 8; ++u)
            v[u] = *(const ushort4*)(Hl + (size_t)csr_src[e + u] * F);
#pragma unroll
        for (int u = 0; u < 8; ++u) {
            acc0 += bf2f(v[u].x); acc1 += bf2f(v[u].y);
            acc2 += bf2f(v[u].z); acc3 += bf2f(v[u].w);
        }
    }
    for (; e + 3 < e1; e += 4) {
        ushort4 v[4];
#pragma unroll
        for (int u = 0; u < 4; ++u)
            v[u] = *(const ushort4*)(Hl + (size_t)csr_src[e + u] * F);
#pragma unroll
        for (int u = 0; u < 4; ++u) {
            acc0 += bf2f(v[u].x); acc1 += bf2f(v[u].y);
            acc2 += bf2f(v[u].z); acc3 += bf2f(v[u].w);
        }
    }
    for (; e < e1; ++e) {
        ushort4 v = *(const ushort4*)(Hl + (size_t)csr_src[e] * F);
        acc0 += bf2f(v.x); acc1 += bf2f(v.y); acc2 += bf2f(v.z); acc3 += bf2f(v.w);
    }

    float nd = norm_dst[node];
    float4 o;
    o.x = fmaf(acc0, nd, bias[f0 + 0]);
    o.y = fmaf(acc1, nd, bias[f0 + 1]);
    o.z = fmaf(acc2, nd, bias[f0 + 2]);
    o.w = fmaf(acc3, nd, bias[f0 + 3]);
    *(float4*)(out + (size_t)node * F + f0) = o;
}

// ---------------- launch ----------------
extern "C" void kernel_launch(void* const* d_in, const int* in_sizes, int n_in,
                              void* d_out, int out_size, void* d_ws, size_t ws_size,
                              hipStream_t stream) {
    const float* x   = (const float*)d_in[0];
    const int*   src = (const int*)d_in[1];
    const int*   dst = (const int*)d_in[2];
    const float* W1  = (const float*)d_in[3];
    const float* b1  = (const float*)d_in[4];
    const float* W2  = (const float*)d_in[5];
    const float* b2  = (const float*)d_in[6];
    float* out = (float*)d_out;

    char* ws = (char*)d_ws;
    size_t off = 0;
    auto alloc = [&](size_t bytes) {
        char* p = ws + off;
        off += (bytes + 255) & ~(size_t)255;
        return p;
    };
    float* norm_src  = (float*)alloc(NNODES * 4);
    float* norm_dst  = (float*)alloc(NNODES * 4);
    int*   cell      = (int*)alloc((size_t)NSCAN * 4);
    int*   ssum      = (int*)alloc(512 * 4);
    unsigned int*  tmp1 = (unsigned int*)alloc((size_t)NEDGES * 4);
    unsigned char* tmp2 = (unsigned char*)alloc((size_t)NEDGES);
    int*   row_ptr   = (int*)alloc((NNODES + 16) * 4);
    int*   csr_src   = (int*)alloc(NEDGES * 4);
    unsigned short* h   = (unsigned short*)alloc((size_t)NNODES * FH * 2);
    unsigned short* h1  = (unsigned short*)alloc((size_t)MPAD * FH * 2);
    unsigned short* Wt1 = (unsigned short*)alloc((size_t)FH * KDIM * 2);
    unsigned short* Wt2 = (unsigned short*)alloc((size_t)FOUT * KDIM * 2);
    unsigned short* h2  = h;

    cast_wt_both<<<96, 256, 0, stream>>>(W1, Wt1, W2, Wt2);

    l1_count<<<NB1, 256, 0, stream>>>(src, dst, cell);
    scanA<<<SCANB, 512, 0, stream>>>(cell, ssum, NSCAN);
    scanB<<<1, 512, 0, stream>>>(ssum, SCANB);
    scanC<<<SCANB, 512, 0, stream>>>(cell, ssum, NSCAN);
    l1_scatter<<<NB1, 256, 0, stream>>>(src, dst, cell, tmp1, tmp2);
    l2_dst<<<NBUCK, 256, 0, stream>>>(tmp1, cell, row_ptr, norm_dst, csr_src);
    l2_src<<<NBUCK, 256, 0, stream>>>(tmp2, cell, norm_src);

    // layer 1: h = bf16((x*norm_src) @ W1)
    gemm_mfma<float, true><<<dim3(MPAD / 128, FH / 128), 256, 0, stream>>>(x, Wt1, norm_src, h, FH);
    agg1_kernel<<<MPAD / 4, 256, 0, stream>>>(h, row_ptr, csr_src, norm_dst, norm_src, b1, h1);

    // layer 2
    gemm_mfma<unsigned short, false><<<dim3(MPAD / 128, FOUT / 128), 256, 0, stream>>>(h1, Wt2, nullptr, h2, FOUT);
    agg2_kernel<<<(NNODES + 7) / 8, 256, 0, stream>>>(h2, row_ptr, csr_src, norm_dst, b2, out);
}